// Round 1
// 881.544 us; speedup vs baseline: 1.3889x; 1.3889x over previous
//
#include <hip/hip_runtime.h>
#include <hip/hip_bf16.h>

// Problem: BS=8, NF=64, N=2048, J=3, NOUT=64, C=2*NOUT=128
// out = [zbn (8*128*2048 fp32), W (8*2048*2048*3 fp32 pass-through)]
// ws layout: [0, 2MB): X as bf16 (1M elems); [2MB, +1KB): stats S1[128],S2[128],scale[128],shift[128]

#define EPSV 1e-5f
#define ZBN_ELEMS (8*128*2048)

typedef __bf16 bf16x8 __attribute__((ext_vector_type(8)));
typedef float  f32x4  __attribute__((ext_vector_type(4)));
typedef float  f4v    __attribute__((ext_vector_type(4)));

union BF8 { unsigned short u[8]; bf16x8 v; };

__device__ __forceinline__ unsigned short f2bf(float f) {
    unsigned u = __float_as_uint(f);
    u += 0x7fffu + ((u >> 16) & 1u);   // round-to-nearest-even (inputs are finite)
    return (unsigned short)(u >> 16);
}

// ---------------- kernel 1: X fp32 -> bf16, zero stats ----------------
__global__ void prep_kernel(const float* __restrict__ X,
                            unsigned short* __restrict__ Xbf,
                            float* __restrict__ stats) {
    int t = blockIdx.x * 256 + threadIdx.x;      // grid sized exactly to 1048576
    Xbf[t] = f2bf(X[t]);
    if (blockIdx.x == 0 && threadIdx.x < 256) stats[threadIdx.x] = 0.0f;
}

// ---------------- kernel 2: GEMM (W*X^T) + W write-through + conv + stats ----------------
// grid = 1024 blocks (8 b * 128 mtiles of 16 rows), 256 threads (4 waves) -> 4 blocks/CU, 16 waves/CU.
// Each wave computes the FULL 16m x 64f x 3j tile over its K-quarter [w*512, w*512+512);
// partials are tree-reduced through LDS, then all 4 waves run the conv stage.
// MFMA 16x16x32 bf16 layouts (HW-verified per guide):
//   A[m=lane&15][k=(lane>>4)*8+e], B[k=(lane>>4)*8+e][n=lane&15], D: col=lane&15, row=(lane>>4)*4+reg
__global__ __launch_bounds__(256, 4) void gemm_conv_kernel(
    const float* __restrict__ W,
    const unsigned short* __restrict__ Xbf,
    const float* __restrict__ cv1_w, const float* __restrict__ cv1_b,
    const float* __restrict__ cv2_w, const float* __restrict__ cv2_b,
    float* __restrict__ out, float* __restrict__ stats)
{
    // red rows padded 192->196: bank = (784q + ...) % 32 -> 16q pattern -> 2 lanes/bank (free)
    __shared__ float red[2][16][196];             // 25088 B
    __shared__ unsigned short x1s[16][200];       // 6400 B  (rows 400B, 16B-aligned)

    const int tid  = threadIdx.x;
    const int w    = tid >> 6;
    const int lane = tid & 63;
    const int q    = lane >> 4;
    const int l15  = lane & 15;
    const int bx   = blockIdx.x;
    const int b    = bx >> 7;
    const int mt   = bx & 127;

    const int m_global = mt * 16 + l15;                  // A-operand row for this lane
    const float* Wrow = W   + (size_t)(b * 2048 + m_global) * 6144;          // 2048*3 floats per m-row
    float*       Wout = out + (size_t)ZBN_ELEMS + (size_t)(b * 2048 + m_global) * 6144;
    const unsigned short* Xb = Xbf + b * (64 * 2048);
    const int kbase = w * 512;                            // this wave's K-quarter

    f32x4 acc[4][3];
    #pragma unroll
    for (int ft = 0; ft < 4; ++ft)
        #pragma unroll
        for (int j = 0; j < 3; ++j)
            acc[ft][j] = (f32x4)0.0f;

    // ---- K loop: 512 / 32 = 16 steps per wave ----
    #pragma unroll 2
    for (int kt = 0; kt < 16; ++kt) {
        const int n0 = kbase + kt * 32 + q * 8;          // this lane's 8 n-values (k = q*8+e)
        // W: 24 contiguous floats = W[b][m][n0..n0+7][j=0..2]
        const f4v* wp = (const f4v*)(Wrow + n0 * 3);
        f4v wv[6];
        #pragma unroll
        for (int i = 0; i < 6; ++i) wv[i] = __builtin_nontemporal_load(wp + i);
        // write-through W to output. NORMAL stores (not nontemporal): the wave's 6-store
        // sequence fully covers each 384B row chunk, so L2 write-combines to full lines.
        f4v* wo = (f4v*)(Wout + n0 * 3);
        #pragma unroll
        for (int i = 0; i < 6; ++i) wo[i] = wv[i];

        const float* wf = (const float*)wv;
        BF8 a[3];
        #pragma unroll
        for (int j = 0; j < 3; ++j)
            #pragma unroll
            for (int e = 0; e < 8; ++e)
                a[j].u[e] = f2bf(wf[e * 3 + j]);

        BF8 bfr[4];
        #pragma unroll
        for (int ft = 0; ft < 4; ++ft)
            bfr[ft].v = *(const bf16x8*)(Xb + (ft * 16 + l15) * 2048 + n0);  // 16B aligned, L2-hot

        #pragma unroll
        for (int ft = 0; ft < 4; ++ft)
            #pragma unroll
            for (int j = 0; j < 3; ++j)
                acc[ft][j] = __builtin_amdgcn_mfma_f32_16x16x32_bf16(a[j].v, bfr[ft].v, acc[ft][j], 0, 0, 0);
    }

    // ---- tree-reduce the 4 K-quarter partials: (2,3)->(0,1), then 1->0 ----
    // lane (q,l15) owns D elements [m=q*4+r][f=l15] for ft,j -> flat index (q*4+r)*196 + j*64+ft*16+l15
    if (w >= 2) {
        float* buf = (float*)red[w - 2];
        #pragma unroll
        for (int ft = 0; ft < 4; ++ft)
            #pragma unroll
            for (int j = 0; j < 3; ++j)
                #pragma unroll
                for (int r = 0; r < 4; ++r)
                    buf[(q * 4 + r) * 196 + j * 64 + ft * 16 + l15] = acc[ft][j][r];
    }
    __syncthreads();
    if (w < 2) {
        const float* buf = (const float*)red[w];
        #pragma unroll
        for (int ft = 0; ft < 4; ++ft)
            #pragma unroll
            for (int j = 0; j < 3; ++j)
                #pragma unroll
                for (int r = 0; r < 4; ++r)
                    acc[ft][j][r] += buf[(q * 4 + r) * 196 + j * 64 + ft * 16 + l15];
    }
    __syncthreads();
    if (w == 1) {
        float* buf = (float*)red[0];
        #pragma unroll
        for (int ft = 0; ft < 4; ++ft)
            #pragma unroll
            for (int j = 0; j < 3; ++j)
                #pragma unroll
                for (int r = 0; r < 4; ++r)
                    buf[(q * 4 + r) * 196 + j * 64 + ft * 16 + l15] = acc[ft][j][r];
    }
    __syncthreads();
    if (w == 0) {
        const float* buf = (const float*)red[0];
        #pragma unroll
        for (int ft = 0; ft < 4; ++ft)
            #pragma unroll
            for (int j = 0; j < 3; ++j)
                #pragma unroll
                for (int r = 0; r < 4; ++r) {
                    float v = acc[ft][j][r] + buf[(q * 4 + r) * 196 + j * 64 + ft * 16 + l15];
                    x1s[q * 4 + r][j * 64 + ft * 16 + l15] = f2bf(v);
                }
    }
    __syncthreads();

    // ---- conv as second MFMA: zb[c][m] = relu(cvw[c][:] . x1[:][m] + bias) ----
    // wave w handles c-tiles {2w, 2w+1} (32 channels), the single 16-m tile, K=192 (6 k-steps)
    f32x4 acc2[2];
    acc2[0] = (f32x4)0.0f;
    acc2[1] = (f32x4)0.0f;

    #pragma unroll
    for (int kt = 0; kt < 6; ++kt) {
        const int i0 = kt * 32 + q * 8;
        BF8 afr[2];
        #pragma unroll
        for (int ctl = 0; ctl < 2; ++ctl) {
            const int c = (2 * w + ctl) * 16 + l15;
            // channels 0..63 = cv2 (yl1), 64..127 = cv1 (z1)  [concat order in reference]
            const float* wr = (c < 64) ? (cv2_w + c * 192) : (cv1_w + (c - 64) * 192);
            const f4v* wp2 = (const f4v*)(wr + i0);
            f4v w0 = wp2[0], w1 = wp2[1];
            #pragma unroll
            for (int e = 0; e < 4; ++e) {
                afr[ctl].u[e]     = f2bf(w0[e]);
                afr[ctl].u[e + 4] = f2bf(w1[e]);
            }
        }
        BF8 b2;
        b2.v = *(const bf16x8*)(&x1s[l15][i0]);
        #pragma unroll
        for (int ctl = 0; ctl < 2; ++ctl)
            acc2[ctl] = __builtin_amdgcn_mfma_f32_16x16x32_bf16(afr[ctl].v, b2.v, acc2[ctl], 0, 0, 0);
    }

    // ---- bias + relu + store zb + per-channel stats ----
    #pragma unroll
    for (int ctl = 0; ctl < 2; ++ctl) {
        #pragma unroll
        for (int r = 0; r < 4; ++r) {
            const int c = (2 * w + ctl) * 16 + q * 4 + r;
            const float bias = (c < 64) ? cv2_b[c] : cv1_b[c - 64];
            float zv = acc2[ctl][r] + bias;
            zv = fmaxf(zv, 0.0f);
            out[((size_t)(b * 128 + c) << 11) + mt * 16 + l15] = zv;
            float s1 = zv, s2 = zv * zv;
            // butterfly over the 16 lanes holding different m (stays within the q-group)
            #pragma unroll
            for (int msk = 1; msk < 16; msk <<= 1) {
                s1 += __shfl_xor(s1, msk);
                s2 += __shfl_xor(s2, msk);
            }
            if (l15 == 0) {
                atomicAdd(&stats[c], s1);
                atomicAdd(&stats[128 + c], s2);
            }
        }
    }
}

// ---------------- kernel 3: finalize BN scale/shift ----------------
__global__ void finalize_kernel(const float* __restrict__ stats,
                                const float* __restrict__ Nb,
                                const float* __restrict__ gamma,
                                const float* __restrict__ beta,
                                float* __restrict__ ss) {
    int c = threadIdx.x;   // 128 threads
    float total = 0.0f;
    #pragma unroll
    for (int i = 0; i < 8; ++i) total += Nb[i];
    float mean = stats[c] / total;
    float var  = stats[128 + c] / total - mean * mean;
    float inv  = rsqrtf(var + EPSV);
    float sc   = gamma[c] * inv;
    ss[c]       = sc;
    ss[128 + c] = beta[c] - mean * sc;
}

// ---------------- kernel 4: in-place normalize zbn = (zb*sc+sh)*mask ----------------
__global__ void norm_kernel(float* __restrict__ out,
                            const float* __restrict__ ss,
                            const float* __restrict__ mask) {
    int t = blockIdx.x * 256 + threadIdx.x;      // over float4, 524288 total (exact)
    float4 v = ((const float4*)out)[t];
    int row = t >> 9;                            // 512 float4 per (b,c) row
    int c = row & 127;
    int b = row >> 7;
    float sc = ss[c], sh = ss[128 + c];
    float4 mk = ((const float4*)mask)[(b << 9) + (t & 511)];
    float4 r;
    r.x = (v.x * sc + sh) * mk.x;
    r.y = (v.y * sc + sh) * mk.y;
    r.z = (v.z * sc + sh) * mk.z;
    r.w = (v.w * sc + sh) * mk.w;
    ((float4*)out)[t] = r;
}

extern "C" void kernel_launch(void* const* d_in, const int* in_sizes, int n_in,
                              void* d_out, int out_size, void* d_ws, size_t ws_size,
                              hipStream_t stream) {
    const float* X     = (const float*)d_in[0];
    const float* W     = (const float*)d_in[1];
    const float* Nb    = (const float*)d_in[2];
    const float* mask  = (const float*)d_in[3];
    const float* cv1_w = (const float*)d_in[4];
    const float* cv1_b = (const float*)d_in[5];
    const float* cv2_w = (const float*)d_in[6];
    const float* cv2_b = (const float*)d_in[7];
    const float* gamma = (const float*)d_in[8];
    const float* beta  = (const float*)d_in[9];
    float* out = (float*)d_out;

    unsigned short* Xbf = (unsigned short*)d_ws;
    float* stats = (float*)((char*)d_ws + (size_t)2 * 1024 * 1024);  // needs ws >= 2MB+1KB
    float* ss    = stats + 256;

    hipLaunchKernelGGL(prep_kernel,      dim3(4096), dim3(256), 0, stream, X, Xbf, stats);
    hipLaunchKernelGGL(gemm_conv_kernel, dim3(1024), dim3(256), 0, stream,
                       W, Xbf, cv1_w, cv1_b, cv2_w, cv2_b, out, stats);
    hipLaunchKernelGGL(finalize_kernel,  dim3(1),    dim3(128), 0, stream, stats, Nb, gamma, beta, ss);
    hipLaunchKernelGGL(norm_kernel,      dim3(2048), dim3(256), 0, stream, out, ss, mask);
}

// Round 2
// 771.537 us; speedup vs baseline: 1.5869x; 1.1426x over previous
//
#include <hip/hip_runtime.h>
#include <hip/hip_bf16.h>

// Problem: BS=8, NF=64, N=2048, J=3, NOUT=64, C=2*NOUT=128
// out = [zbn (8*128*2048 fp32), W (8*2048*2048*3 fp32 pass-through)]
// ws layout: [0, 2MB): X as bf16 (1M elems); [2MB, +1KB): stats S1[128],S2[128],scale[128],shift[128]

#define EPSV 1e-5f
#define ZBN_ELEMS (8*128*2048)

typedef __bf16 bf16x8 __attribute__((ext_vector_type(8)));
typedef float  f32x4  __attribute__((ext_vector_type(4)));
typedef float  f4v    __attribute__((ext_vector_type(4)));

union BF8 { unsigned short u[8]; bf16x8 v; };
union F4  { float f[4]; f4v v; };

__device__ __forceinline__ unsigned short f2bf(float f) {
    unsigned u = __float_as_uint(f);
    u += 0x7fffu + ((u >> 16) & 1u);   // round-to-nearest-even (inputs are finite)
    return (unsigned short)(u >> 16);
}

// ---------------- kernel 1: X fp32 -> bf16, zero stats ----------------
__global__ void prep_kernel(const float* __restrict__ X,
                            unsigned short* __restrict__ Xbf,
                            float* __restrict__ stats) {
    int t = blockIdx.x * 256 + threadIdx.x;      // grid sized exactly to 1048576
    Xbf[t] = f2bf(X[t]);
    if (blockIdx.x == 0 && threadIdx.x < 256) stats[threadIdx.x] = 0.0f;
}

// ---------------- kernel 2: GEMM (W*X^T) + W write-through + conv + stats ----------------
// grid = 1024 blocks (8 b * 128 mtiles of 16 rows), 256 threads (4 waves), 4 blocks/CU.
// Per K-tile of 128 cols: the block stages W[16m][128n][3j] (24KB) with FLAT chunk-contiguous
// global loads (each wave-instruction covers 1KB contiguous -> ~8 requests vs ~64 before),
// stores the identical flat layout to out (W pass-through), and scatters bf16 into a padded
// [j][16][136] LDS tile. Waves split the f-dimension (wave w owns f=w*16..+16), each
// accumulating the FULL K=2048 -> no cross-wave reduction needed.
// MFMA 16x16x32 bf16 layouts (HW-verified per guide):
//   A[m=lane&15][k=(lane>>4)*8+e], B[k=(lane>>4)*8+e][n=lane&15], D: col=lane&15, row=(lane>>4)*4+reg
__global__ __launch_bounds__(256, 4) void gemm_conv_kernel(
    const float* __restrict__ W,
    const unsigned short* __restrict__ Xbf,
    const float* __restrict__ cv1_w, const float* __restrict__ cv1_b,
    const float* __restrict__ cv2_w, const float* __restrict__ cv2_b,
    float* __restrict__ out, float* __restrict__ stats)
{
    __shared__ unsigned short wt[3][16][136];    // 13056 B, pad 128->136: ds_read_b128 2-way aliasing (free)
    __shared__ unsigned short x1s[16][200];      // 6400 B (rows 400B, 16B-aligned)

    const int tid  = threadIdx.x;
    const int w    = tid >> 6;
    const int lane = tid & 63;
    const int q    = lane >> 4;
    const int l15  = lane & 15;
    const int b    = blockIdx.x >> 7;
    const int mt   = blockIdx.x & 127;

    const float* Wbase  = W   + (size_t)(b * 2048 + mt * 16) * 6144;
    float*       Wobase = out + (size_t)ZBN_ELEMS + (size_t)(b * 2048 + mt * 16) * 6144;
    const unsigned short* Xrow = Xbf + (size_t)b * (64 * 2048) + (w * 16 + l15) * 2048;

    // ---- per-thread flat-chunk decode (loop-invariant; compiler hoists) ----
    // tile = 16 rows x 384 floats/row (128 n x 3 j) = 1536 chunks of 16B; thread owns c = tid + 256*i
    int gofs[6];   // global float offset within tile-0 (row r: +r*6144; within row: +o4)
    int crow[6], co4[6];
    #pragma unroll
    for (int i = 0; i < 6; ++i) {
        int c  = tid + 256 * i;
        int r  = c / 96;               // 96 chunks per row
        int o4 = (c - r * 96) * 4;     // within-row float offset (0..380)
        crow[i] = r; co4[i] = o4;
        gofs[i] = r * 6144 + o4;
    }

    f32x4 acc[3];
    acc[0] = (f32x4)0.0f; acc[1] = (f32x4)0.0f; acc[2] = (f32x4)0.0f;

    // process one staged tile: copy-through + LDS scatter + MFMA
    auto process = [&](F4 (&buf)[6], int t) {
        // W write-through: identical flat addressing -> fully coalesced stores
        #pragma unroll
        for (int i = 0; i < 6; ++i)
            *(f4v*)(Wobase + t * 384 + gofs[i]) = buf[i].v;
        // scatter to LDS as bf16 in [j][16][136] layout
        #pragma unroll
        for (int i = 0; i < 6; ++i) {
            #pragma unroll
            for (int u = 0; u < 4; ++u) {
                int o = co4[i] + u;
                int n = o / 3;
                int j = o - n * 3;
                ((unsigned short*)wt)[(j * 16 + crow[i]) * 136 + n] = f2bf(buf[i].f[u]);
            }
        }
        __syncthreads();
        // MFMA phase: A-fragments via ds_read_b128, B-fragments (X) from L2-hot global
        BF8 bfr[4];
        #pragma unroll
        for (int kk = 0; kk < 4; ++kk)
            bfr[kk].v = *(const bf16x8*)(Xrow + t * 128 + kk * 32 + q * 8);
        #pragma unroll
        for (int kk = 0; kk < 4; ++kk) {
            #pragma unroll
            for (int j = 0; j < 3; ++j) {
                bf16x8 af = *(const bf16x8*)&wt[j][l15][kk * 32 + q * 8];
                acc[j] = __builtin_amdgcn_mfma_f32_16x16x32_bf16(af, bfr[kk].v, acc[j], 0, 0, 0);
            }
        }
        __syncthreads();
    };

    // ---- K loop: 16 tiles of 128 cols, register-double-buffered prefetch ----
    F4 bufA[6], bufB[6];
    #pragma unroll
    for (int i = 0; i < 6; ++i)
        bufA[i].v = __builtin_nontemporal_load((const f4v*)(Wbase + gofs[i]));

    #pragma unroll 1
    for (int tt = 0; tt < 8; ++tt) {
        const int t0 = 2 * tt, t1 = 2 * tt + 1;
        #pragma unroll
        for (int i = 0; i < 6; ++i)
            bufB[i].v = __builtin_nontemporal_load((const f4v*)(Wbase + t1 * 384 + gofs[i]));
        process(bufA, t0);
        if (tt < 7) {
            #pragma unroll
            for (int i = 0; i < 6; ++i)
                bufA[i].v = __builtin_nontemporal_load((const f4v*)(Wbase + (t1 + 1) * 384 + gofs[i]));
        }
        process(bufB, t1);
    }

    // ---- spill x1 tile to LDS: x1s[m][i=j*64+f], wave w owns f = w*16+l15 ----
    #pragma unroll
    for (int j = 0; j < 3; ++j)
        #pragma unroll
        for (int r = 0; r < 4; ++r)
            x1s[q * 4 + r][j * 64 + w * 16 + l15] = f2bf(acc[j][r]);
    __syncthreads();

    // ---- conv as second MFMA: zb[c][m] = relu(cvw[c][:] . x1[:][m] + bias) ----
    // wave w handles c-tiles {2w, 2w+1} (32 channels), the single 16-m tile, K=192 (6 k-steps)
    f32x4 acc2[2];
    acc2[0] = (f32x4)0.0f;
    acc2[1] = (f32x4)0.0f;

    #pragma unroll
    for (int kt = 0; kt < 6; ++kt) {
        const int i0 = kt * 32 + q * 8;
        BF8 afr[2];
        #pragma unroll
        for (int ctl = 0; ctl < 2; ++ctl) {
            const int c = (2 * w + ctl) * 16 + l15;
            // channels 0..63 = cv2 (yl1), 64..127 = cv1 (z1)  [concat order in reference]
            const float* wr = (c < 64) ? (cv2_w + c * 192) : (cv1_w + (c - 64) * 192);
            const f4v* wp2 = (const f4v*)(wr + i0);
            f4v w0 = wp2[0], w1 = wp2[1];
            #pragma unroll
            for (int e = 0; e < 4; ++e) {
                afr[ctl].u[e]     = f2bf(w0[e]);
                afr[ctl].u[e + 4] = f2bf(w1[e]);
            }
        }
        BF8 b2;
        b2.v = *(const bf16x8*)(&x1s[l15][i0]);
        #pragma unroll
        for (int ctl = 0; ctl < 2; ++ctl)
            acc2[ctl] = __builtin_amdgcn_mfma_f32_16x16x32_bf16(afr[ctl].v, b2.v, acc2[ctl], 0, 0, 0);
    }

    // ---- bias + relu + store zb + per-channel stats ----
    #pragma unroll
    for (int ctl = 0; ctl < 2; ++ctl) {
        #pragma unroll
        for (int r = 0; r < 4; ++r) {
            const int c = (2 * w + ctl) * 16 + q * 4 + r;
            const float bias = (c < 64) ? cv2_b[c] : cv1_b[c - 64];
            float zv = acc2[ctl][r] + bias;
            zv = fmaxf(zv, 0.0f);
            out[((size_t)(b * 128 + c) << 11) + mt * 16 + l15] = zv;
            float s1 = zv, s2 = zv * zv;
            // butterfly over the 16 lanes holding different m (stays within the q-group)
            #pragma unroll
            for (int msk = 1; msk < 16; msk <<= 1) {
                s1 += __shfl_xor(s1, msk);
                s2 += __shfl_xor(s2, msk);
            }
            if (l15 == 0) {
                atomicAdd(&stats[c], s1);
                atomicAdd(&stats[128 + c], s2);
            }
        }
    }
}

// ---------------- kernel 3: finalize BN scale/shift ----------------
__global__ void finalize_kernel(const float* __restrict__ stats,
                                const float* __restrict__ Nb,
                                const float* __restrict__ gamma,
                                const float* __restrict__ beta,
                                float* __restrict__ ss) {
    int c = threadIdx.x;   // 128 threads
    float total = 0.0f;
    #pragma unroll
    for (int i = 0; i < 8; ++i) total += Nb[i];
    float mean = stats[c] / total;
    float var  = stats[128 + c] / total - mean * mean;
    float inv  = rsqrtf(var + EPSV);
    float sc   = gamma[c] * inv;
    ss[c]       = sc;
    ss[128 + c] = beta[c] - mean * sc;
}

// ---------------- kernel 4: in-place normalize zbn = (zb*sc+sh)*mask ----------------
__global__ void norm_kernel(float* __restrict__ out,
                            const float* __restrict__ ss,
                            const float* __restrict__ mask) {
    int t = blockIdx.x * 256 + threadIdx.x;      // over float4, 524288 total (exact)
    float4 v = ((const float4*)out)[t];
    int row = t >> 9;                            // 512 float4 per (b,c) row
    int c = row & 127;
    int b = row >> 7;
    float sc = ss[c], sh = ss[128 + c];
    float4 mk = ((const float4*)mask)[(b << 9) + (t & 511)];
    float4 r;
    r.x = (v.x * sc + sh) * mk.x;
    r.y = (v.y * sc + sh) * mk.y;
    r.z = (v.z * sc + sh) * mk.z;
    r.w = (v.w * sc + sh) * mk.w;
    ((float4*)out)[t] = r;
}

extern "C" void kernel_launch(void* const* d_in, const int* in_sizes, int n_in,
                              void* d_out, int out_size, void* d_ws, size_t ws_size,
                              hipStream_t stream) {
    const float* X     = (const float*)d_in[0];
    const float* W     = (const float*)d_in[1];
    const float* Nb    = (const float*)d_in[2];
    const float* mask  = (const float*)d_in[3];
    const float* cv1_w = (const float*)d_in[4];
    const float* cv1_b = (const float*)d_in[5];
    const float* cv2_w = (const float*)d_in[6];
    const float* cv2_b = (const float*)d_in[7];
    const float* gamma = (const float*)d_in[8];
    const float* beta  = (const float*)d_in[9];
    float* out = (float*)d_out;

    unsigned short* Xbf = (unsigned short*)d_ws;
    float* stats = (float*)((char*)d_ws + (size_t)2 * 1024 * 1024);  // needs ws >= 2MB+1KB
    float* ss    = stats + 256;

    hipLaunchKernelGGL(prep_kernel,      dim3(4096), dim3(256), 0, stream, X, Xbf, stats);
    hipLaunchKernelGGL(gemm_conv_kernel, dim3(1024), dim3(256), 0, stream,
                       W, Xbf, cv1_w, cv1_b, cv2_w, cv2_b, out, stats);
    hipLaunchKernelGGL(finalize_kernel,  dim3(1),    dim3(128), 0, stream, stats, Nb, gamma, beta, ss);
    hipLaunchKernelGGL(norm_kernel,      dim3(2048), dim3(256), 0, stream, out, ss, mask);
}